// Round 1
// baseline (174.734 us; speedup 1.0000x reference)
//
#include <hip/hip_runtime.h>
#include <math.h>

#define N 4096
#define D 128
#define TI 4

#define POS_W 2.0f
#define NEG_W 40.0f
#define MARGIN 0.1f
#define THRESH 0.5f

// ---------------- wave-level reductions (wave64) ----------------
__device__ __forceinline__ float wsum(float v) {
#pragma unroll
  for (int off = 32; off > 0; off >>= 1) v += __shfl_xor(v, off);
  return v;
}
__device__ __forceinline__ float wminr(float v) {
#pragma unroll
  for (int off = 32; off > 0; off >>= 1) v = fminf(v, __shfl_xor(v, off));
  return v;
}
__device__ __forceinline__ float wmaxr(float v) {
#pragma unroll
  for (int off = 32; off > 0; off >>= 1) v = fmaxf(v, __shfl_xor(v, off));
  return v;
}
__device__ __forceinline__ int wor(int v) {
#pragma unroll
  for (int off = 32; off > 0; off >>= 1) v |= __shfl_xor(v, off);
  return v;
}

// ---------------- K1: L2-normalize rows; emit row-major + transposed ----------------
__global__ __launch_bounds__(256) void k_normalize(const float* __restrict__ x,
                                                   float* __restrict__ xn,
                                                   float* __restrict__ xT) {
  __shared__ float tile[TI][D];
  const int t = threadIdx.x;
  const int wv = t >> 6, lane = t & 63;
  const int i0 = blockIdx.x * TI;
  const int row = i0 + wv;

  float2 v = *(const float2*)&x[row * D + lane * 2];
  float ss = v.x * v.x + v.y * v.y;
  ss = wsum(ss);
  const float rn = rsqrtf(ss);
  const float a = v.x * rn, b = v.y * rn;
  *(float2*)&xn[row * D + lane * 2] = make_float2(a, b);
  tile[wv][lane * 2] = a;
  tile[wv][lane * 2 + 1] = b;
  __syncthreads();
  // write transposed: xT[d][i0+c] = tile[c][d]; 512 elems, 2 iterations
  for (int idx = t; idx < TI * D; idx += 256) {
    const int d = idx >> 2, c = idx & 3;
    xT[d * N + i0 + c] = tile[c][d];
  }
}

// ---------------- K2: per-4-row S tile in LDS, two mining passes ----------------
__global__ __launch_bounds__(256) void k_main(const float* __restrict__ xn,
                                              const float* __restrict__ xT,
                                              const int* __restrict__ labels,
                                              float* __restrict__ row_pos,
                                              float* __restrict__ row_neg,
                                              float* __restrict__ row_valid) {
  __shared__ float S[TI][N];      // 64 KB
  __shared__ float xi[TI][D];     // 2 KB
  __shared__ int labi[TI];
  __shared__ float red_a[TI][4], red_b[TI][4];
  __shared__ int red_i[4];
  __shared__ float mp_sh[TI], mn_sh[TI];

  const int t = threadIdx.x;
  const int wv = t >> 6, lane = t & 63;
  const int i0 = blockIdx.x * TI;

  for (int idx = t; idx < TI * D; idx += 256)
    xi[idx >> 7][idx & (D - 1)] = xn[i0 * D + idx];
  if (t < TI) labi[t] = labels[i0 + t];
  __syncthreads();

  // ---- compute S[0..3][0..4095] ----
  for (int jg = 0; jg < 4; ++jg) {
    const int j0 = (jg << 10) + (t << 2);
    float4 acc0 = {0, 0, 0, 0}, acc1 = {0, 0, 0, 0}, acc2 = {0, 0, 0, 0}, acc3 = {0, 0, 0, 0};
#pragma unroll 2
    for (int d4 = 0; d4 < D / 4; ++d4) {
      const float4 a0 = *(const float4*)&xi[0][d4 * 4];
      const float4 a1 = *(const float4*)&xi[1][d4 * 4];
      const float4 a2 = *(const float4*)&xi[2][d4 * 4];
      const float4 a3 = *(const float4*)&xi[3][d4 * 4];
#pragma unroll
      for (int k = 0; k < 4; ++k) {
        const float4 bv = *(const float4*)&xT[(d4 * 4 + k) * N + j0];
        const float f0 = ((const float*)&a0)[k];
        const float f1 = ((const float*)&a1)[k];
        const float f2 = ((const float*)&a2)[k];
        const float f3 = ((const float*)&a3)[k];
        acc0.x += f0 * bv.x; acc0.y += f0 * bv.y; acc0.z += f0 * bv.z; acc0.w += f0 * bv.w;
        acc1.x += f1 * bv.x; acc1.y += f1 * bv.y; acc1.z += f1 * bv.z; acc1.w += f1 * bv.w;
        acc2.x += f2 * bv.x; acc2.y += f2 * bv.y; acc2.z += f2 * bv.z; acc2.w += f2 * bv.w;
        acc3.x += f3 * bv.x; acc3.y += f3 * bv.y; acc3.z += f3 * bv.z; acc3.w += f3 * bv.w;
      }
    }
    *(float4*)&S[0][j0] = acc0;
    *(float4*)&S[1][j0] = acc1;
    *(float4*)&S[2][j0] = acc2;
    *(float4*)&S[3][j0] = acc3;
  }
  __syncthreads();

  const int li0 = labi[0], li1 = labi[1], li2 = labi[2], li3 = labi[3];

  // ---- pass 1: min_pos / max_neg per row ----
  float mp[TI], mn[TI];
#pragma unroll
  for (int i = 0; i < TI; ++i) { mp[i] = 1e9f; mn[i] = -1e9f; }
  int jlab[16];
#pragma unroll
  for (int k = 0; k < 16; ++k) {
    const int j = t + k * 256;
    const int lj = labels[j];
    jlab[k] = lj;
    const int lref[TI] = {li0, li1, li2, li3};
#pragma unroll
    for (int i = 0; i < TI; ++i) {
      const float s = S[i][j];
      if (lj == lref[i]) {
        if (j != i0 + i) mp[i] = fminf(mp[i], s);
      } else {
        mn[i] = fmaxf(mn[i], s);
      }
    }
  }
#pragma unroll
  for (int i = 0; i < TI; ++i) { mp[i] = wminr(mp[i]); mn[i] = wmaxr(mn[i]); }
  if (lane == 0) {
#pragma unroll
    for (int i = 0; i < TI; ++i) { red_a[i][wv] = mp[i]; red_b[i][wv] = mn[i]; }
  }
  __syncthreads();
  if (t < TI) {
    mp_sh[t] = fminf(fminf(red_a[t][0], red_a[t][1]), fminf(red_a[t][2], red_a[t][3]));
    mn_sh[t] = fmaxf(fmaxf(red_b[t][0], red_b[t][1]), fmaxf(red_b[t][2], red_b[t][3]));
  }
  __syncthreads();

  const float mpf[TI] = {mp_sh[0], mp_sh[1], mp_sh[2], mp_sh[3]};
  const float mnf[TI] = {mn_sh[0], mn_sh[1], mn_sh[2], mn_sh[3]};

  // ---- pass 2: mined exp sums ----
  float ps[TI] = {0, 0, 0, 0}, ns[TI] = {0, 0, 0, 0};
  int flags = 0;  // bit i: pos_sel any for row i; bit i+4: neg_sel any
#pragma unroll
  for (int k = 0; k < 16; ++k) {
    const int j = t + k * 256;
    const int lj = jlab[k];
    const int lref[TI] = {li0, li1, li2, li3};
#pragma unroll
    for (int i = 0; i < TI; ++i) {
      const float s = S[i][j];
      if (lj == lref[i]) {
        if (j != i0 + i && (s - MARGIN < mnf[i])) {
          ps[i] += __expf(-POS_W * (s - THRESH));
          flags |= (1 << i);
        }
      } else {
        if (s + MARGIN > mpf[i]) {
          ns[i] += __expf(NEG_W * (s - THRESH));
          flags |= (1 << (i + 4));
        }
      }
    }
  }
#pragma unroll
  for (int i = 0; i < TI; ++i) { ps[i] = wsum(ps[i]); ns[i] = wsum(ns[i]); }
  flags = wor(flags);
  if (lane == 0) {
#pragma unroll
    for (int i = 0; i < TI; ++i) { red_a[i][wv] = ps[i]; red_b[i][wv] = ns[i]; }
    red_i[wv] = flags;
  }
  __syncthreads();
  if (t < TI) {
    const float pst = red_a[t][0] + red_a[t][1] + red_a[t][2] + red_a[t][3];
    const float nst = red_b[t][0] + red_b[t][1] + red_b[t][2] + red_b[t][3];
    const int fl = red_i[0] | red_i[1] | red_i[2] | red_i[3];
    const bool posany = mp_sh[t] < 1e8f;
    const bool negany = mn_sh[t] > -1e8f;
    const bool valid = posany && negany && (fl & (1 << t)) && (fl & (1 << (t + 4)));
    const int row = i0 + t;
    row_pos[row] = valid ? (log1pf(pst) / POS_W) : 0.f;
    row_neg[row] = valid ? (log1pf(nst) / NEG_W) : 0.f;
    row_valid[row] = valid ? 1.f : 0.f;
  }
}

// ---------------- K3: final reduction ----------------
__global__ __launch_bounds__(256) void k_finalize(const float* __restrict__ rp,
                                                  const float* __restrict__ rn,
                                                  const float* __restrict__ rv,
                                                  float* __restrict__ out) {
  __shared__ float red[3][4];
  const int t = threadIdx.x;
  float sp = 0.f, sn = 0.f, sc = 0.f;
  for (int i = t; i < N; i += 256) { sp += rp[i]; sn += rn[i]; sc += rv[i]; }
  sp = wsum(sp); sn = wsum(sn); sc = wsum(sc);
  if ((t & 63) == 0) { red[0][t >> 6] = sp; red[1][t >> 6] = sn; red[2][t >> 6] = sc; }
  __syncthreads();
  if (t == 0) {
    const float tp = red[0][0] + red[0][1] + red[0][2] + red[0][3];
    const float tn = red[1][0] + red[1][1] + red[1][2] + red[1][3];
    const float tc = red[2][0] + red[2][1] + red[2][2] + red[2][3];
    const float cnt = fmaxf(tc, 1.f);
    const float pm = tp / cnt, nm = tn / cnt;
    out[0] = pm + nm;
    out[1] = pm;
    out[2] = nm;
  }
}

extern "C" void kernel_launch(void* const* d_in, const int* in_sizes, int n_in,
                              void* d_out, int out_size, void* d_ws, size_t ws_size,
                              hipStream_t stream) {
  const float* batch = (const float*)d_in[0];
  const int* labels = (const int*)d_in[1];
  float* out = (float*)d_out;

  float* ws = (float*)d_ws;
  float* xn = ws;                 // N*D floats
  float* xT = ws + (size_t)N * D; // D*N floats
  float* rp = ws + (size_t)2 * N * D;
  float* rn = rp + N;
  float* rv = rn + N;

  k_normalize<<<N / TI, 256, 0, stream>>>(batch, xn, xT);
  k_main<<<N / TI, 256, 0, stream>>>(xn, xT, labels, rp, rn, rv);
  k_finalize<<<1, 256, 0, stream>>>(rp, rn, rv, out);
}

// Round 2
// 112.829 us; speedup vs baseline: 1.5487x; 1.5487x over previous
//
#include <hip/hip_runtime.h>
#include <hip/hip_bf16.h>
#include <math.h>

#define N 4096
#define D 128
#define POS_W 2.0f
#define NEG_W 40.0f
#define MARGIN 0.1f
#define THRESH 0.5f

typedef __bf16 bf16x8 __attribute__((ext_vector_type(8)));
typedef float f32x4 __attribute__((ext_vector_type(4)));
typedef unsigned int uint32;

// order-preserving float<->uint encoding (for atomicMin/Max)
__device__ __forceinline__ uint32 enc_f(float f) {
  uint32 u = __float_as_uint(f);
  return (u & 0x80000000u) ? ~u : (u | 0x80000000u);
}
__device__ __forceinline__ float dec_f(uint32 e) {
  uint32 u = (e & 0x80000000u) ? (e & 0x7FFFFFFFu) : ~e;
  return __uint_as_float(u);
}

// ---------------- K1: L2-normalize rows -> bf16 ----------------
__global__ __launch_bounds__(256) void k_normalize(const float* __restrict__ x,
                                                   ushort* __restrict__ xn) {
  const int t = threadIdx.x, wv = t >> 6, lane = t & 63;
  const int row = blockIdx.x * 4 + wv;
  float2 v = *(const float2*)&x[row * D + lane * 2];
  float ss = v.x * v.x + v.y * v.y;
#pragma unroll
  for (int off = 32; off; off >>= 1) ss += __shfl_xor(ss, off);
  const float rn = rsqrtf(ss);
  __hip_bfloat162 o;
  o.x = __float2bfloat16(v.x * rn);
  o.y = __float2bfloat16(v.y * rn);
  *(__hip_bfloat162*)&xn[row * D + lane * 2] = o;
}

// ---------------- K2/K3: MFMA 128x128 tile, mining epilogues ----------------
// PASS 0: per-row min_pos / max_neg  -> atomicMin/Max (encoded)
// PASS 1: mined exp sums             -> atomicAdd
template <int PASS>
__global__ __launch_bounds__(256) void k_pass(const ushort* __restrict__ xn,
                                              const int* __restrict__ labels,
                                              uint32* __restrict__ mp_enc,
                                              uint32* __restrict__ mn_enc,
                                              float* __restrict__ rp,
                                              float* __restrict__ rn) {
  __shared__ ushort Abuf[128 * 128];  // 32 KB, [row][k] bf16, XOR-swizzled
  __shared__ ushort Bbuf[128 * 128];  // 32 KB
  __shared__ int labi[128], labj[128];
  __shared__ float redA[128][2], redB[128][2];
  __shared__ float mpS[128], mnS[128];

  const int t = threadIdx.x;
  const int w = t >> 6, lane = t & 63;
  const int ib = blockIdx.x >> 5, jb = blockIdx.x & 31;
  const int i0 = ib * 128, j0 = jb * 128;

  if (t < 128) {
    labi[t] = labels[i0 + t];
    labj[t] = labels[j0 + t];
    if (PASS == 1) {
      mpS[t] = dec_f(mp_enc[i0 + t]);
      mnS[t] = dec_f(mn_enc[i0 + t]);
    }
  }

  // stage A (rows i0..) and B (rows j0..) tiles; swizzled ds_write, linear global
  {
    const char* gA = (const char*)(xn + (size_t)i0 * D);
    const char* gB = (const char*)(xn + (size_t)j0 * D);
#pragma unroll
    for (int it = 0; it < 8; ++it) {
      const int L = (t + it * 256) * 16;         // linear byte offset in 32KB tile
      const int Ls = L ^ (((L >> 8) & 7) << 4);  // bank-conflict swizzle
      const f32x4 a = *(const f32x4*)(gA + L);
      const f32x4 b = *(const f32x4*)(gB + L);
      *(f32x4*)((char*)Abuf + Ls) = a;
      *(f32x4*)((char*)Bbuf + Ls) = b;
    }
  }
  __syncthreads();

  const int wm = w >> 1, wn = w & 1;
  const int lr = lane & 15, lk = lane >> 4;

  f32x4 acc[4][4];
#pragma unroll
  for (int m = 0; m < 4; ++m)
#pragma unroll
    for (int n = 0; n < 4; ++n) acc[m][n] = (f32x4){0.f, 0.f, 0.f, 0.f};

#pragma unroll
  for (int ks = 0; ks < 4; ++ks) {
    bf16x8 af[4], bg[4];
#pragma unroll
    for (int m = 0; m < 4; ++m) {
      const int rowb = wm * 64 + m * 16 + lr;
      int off = rowb * 256 + ks * 64 + lk * 16;
      off ^= ((rowb & 7) << 4);
      af[m] = *(const bf16x8*)((const char*)Abuf + off);
    }
#pragma unroll
    for (int n = 0; n < 4; ++n) {
      const int rowb = wn * 64 + n * 16 + lr;
      int off = rowb * 256 + ks * 64 + lk * 16;
      off ^= ((rowb & 7) << 4);
      bg[n] = *(const bf16x8*)((const char*)Bbuf + off);
    }
#pragma unroll
    for (int m = 0; m < 4; ++m)
#pragma unroll
      for (int n = 0; n < 4; ++n)
        acc[m][n] = __builtin_amdgcn_mfma_f32_16x16x32_bf16(af[m], bg[n], acc[m][n], 0, 0, 0);
  }

  // C layout: col = lane&15, row = (lane>>4)*4 + reg   (m89-verified)
  int ljr[4];
#pragma unroll
  for (int n = 0; n < 4; ++n) ljr[n] = labj[wn * 64 + n * 16 + lr];

#pragma unroll
  for (int m = 0; m < 4; ++m) {
#pragma unroll
    for (int r = 0; r < 4; ++r) {
      const int rl = wm * 64 + m * 16 + lk * 4 + r;  // local row
      const int li = labi[rl];
      const int gi = i0 + rl;
      if (PASS == 0) {
        float pmin = 1e9f, nmax = -1e9f;
#pragma unroll
        for (int n = 0; n < 4; ++n) {
          const int cl = wn * 64 + n * 16 + lr;
          const float s = acc[m][n][r];
          if (ljr[n] == li) {
            if (gi != j0 + cl) pmin = fminf(pmin, s);
          } else {
            nmax = fmaxf(nmax, s);
          }
        }
#pragma unroll
        for (int o = 1; o < 16; o <<= 1) {
          pmin = fminf(pmin, __shfl_xor(pmin, o));
          nmax = fmaxf(nmax, __shfl_xor(nmax, o));
        }
        if (lr == 0) { redA[rl][wn] = pmin; redB[rl][wn] = nmax; }
      } else {
        const float mp = mpS[rl], mx = mnS[rl];
        float psum = 0.f, nsum = 0.f;
#pragma unroll
        for (int n = 0; n < 4; ++n) {
          const int cl = wn * 64 + n * 16 + lr;
          const float s = acc[m][n][r];
          if (ljr[n] == li) {
            if ((gi != j0 + cl) && (s - MARGIN < mx)) psum += __expf(-POS_W * (s - THRESH));
          } else {
            if (s + MARGIN > mp) nsum += __expf(NEG_W * (s - THRESH));
          }
        }
#pragma unroll
        for (int o = 1; o < 16; o <<= 1) {
          psum += __shfl_xor(psum, o);
          nsum += __shfl_xor(nsum, o);
        }
        if (lr == 0) { redA[rl][wn] = psum; redB[rl][wn] = nsum; }
      }
    }
  }
  __syncthreads();
  if (t < 128) {
    if (PASS == 0) {
      atomicMin(&mp_enc[i0 + t], enc_f(fminf(redA[t][0], redA[t][1])));
      atomicMax(&mn_enc[i0 + t], enc_f(fmaxf(redB[t][0], redB[t][1])));
    } else {
      atomicAdd(&rp[i0 + t], redA[t][0] + redA[t][1]);
      atomicAdd(&rn[i0 + t], redB[t][0] + redB[t][1]);
    }
  }
}

// ---------------- K4: final reduction ----------------
__global__ __launch_bounds__(256) void k_finalize(const uint32* __restrict__ mp_enc,
                                                  const uint32* __restrict__ mn_enc,
                                                  const float* __restrict__ rp,
                                                  const float* __restrict__ rn,
                                                  float* __restrict__ out) {
  __shared__ float red[3][4];
  const int t = threadIdx.x, wv = t >> 6, lane = t & 63;
  float sp = 0.f, sn = 0.f, sc = 0.f;
  for (int i = t; i < N; i += 256) {
    const float mp = dec_f(mp_enc[i]);
    const float mx = dec_f(mn_enc[i]);
    const float p = rp[i], ng = rn[i];
    const bool valid = (mp < 1e8f) && (mx > -1e8f) && (p > 0.f) && (ng > 0.f);
    if (valid) {
      sp += log1pf(p) * (1.0f / POS_W);
      sn += log1pf(ng) * (1.0f / NEG_W);
      sc += 1.f;
    }
  }
#pragma unroll
  for (int off = 32; off; off >>= 1) {
    sp += __shfl_xor(sp, off);
    sn += __shfl_xor(sn, off);
    sc += __shfl_xor(sc, off);
  }
  if (lane == 0) { red[0][wv] = sp; red[1][wv] = sn; red[2][wv] = sc; }
  __syncthreads();
  if (t == 0) {
    const float tp = red[0][0] + red[0][1] + red[0][2] + red[0][3];
    const float tn = red[1][0] + red[1][1] + red[1][2] + red[1][3];
    const float tc = red[2][0] + red[2][1] + red[2][2] + red[2][3];
    const float cnt = fmaxf(tc, 1.f);
    const float pm = tp / cnt, nm = tn / cnt;
    out[0] = pm + nm;
    out[1] = pm;
    out[2] = nm;
  }
}

extern "C" void kernel_launch(void* const* d_in, const int* in_sizes, int n_in,
                              void* d_out, int out_size, void* d_ws, size_t ws_size,
                              hipStream_t stream) {
  const float* batch = (const float*)d_in[0];
  const int* labels = (const int*)d_in[1];
  float* out = (float*)d_out;

  char* ws = (char*)d_ws;
  ushort* xn = (ushort*)ws;                          // N*D bf16 = 1 MB
  uint32* mp_enc = (uint32*)(ws + (size_t)N * D * 2);  // N u32
  uint32* mn_enc = mp_enc + N;                       // N u32   (zeroed)
  float* rp = (float*)(mn_enc + N);                  // N f32   (zeroed)
  float* rn = rp + N;                                // N f32   (zeroed)

  // init: min -> 0xFFFFFFFF (max uint); max/sums -> 0
  hipMemsetAsync(mp_enc, 0xFF, N * sizeof(uint32), stream);
  hipMemsetAsync(mn_enc, 0x00, N * sizeof(uint32) + 2 * N * sizeof(float), stream);

  k_normalize<<<N / 4, 256, 0, stream>>>(batch, xn);
  k_pass<0><<<1024, 256, 0, stream>>>(xn, labels, mp_enc, mn_enc, rp, rn);
  k_pass<1><<<1024, 256, 0, stream>>>(xn, labels, mp_enc, mn_enc, rp, rn);
  k_finalize<<<1, 256, 0, stream>>>(mp_enc, mn_enc, rp, rn, out);
}